// Round 15
// baseline (455.007 us; speedup 1.0000x reference)
//
#include <hip/hip_runtime.h>
#include <stdint.h>

#define HW 4096
#define NC 512
#define NB 4

typedef __attribute__((ext_vector_type(8))) _Float16 f16x8;
typedef __attribute__((ext_vector_type(4))) float f32x4;
typedef __attribute__((ext_vector_type(4))) unsigned short ush4;
typedef __attribute__((ext_vector_type(8))) unsigned short ush8;

typedef __attribute__((address_space(1))) const void* as1_cvp;
typedef __attribute__((address_space(3))) void* as3_vp;

__device__ __forceinline__ unsigned short f2h(float f) {
  union { _Float16 h; unsigned short u; } c;
  c.h = (_Float16)f;           // hardware v_cvt_f16_f32, RNE
  return c.u;
}
__device__ __forceinline__ float h2f(unsigned short u) {
  union { unsigned short u; _Float16 h; } c;
  c.u = u;
  return (float)c.h;
}

// ---------------- moments: per-(b,c) mean/rstd over 4096 spatial elems ----------
__global__ __launch_bounds__(256) void moments_k(const float* __restrict__ x,
                                                 const float* __restrict__ y,
                                                 float* __restrict__ stats) {
  int bid = blockIdx.x;          // 0..4095 : [tensor(2)][b*C+c (2048)]
  int tens = bid >> 11;
  int row = bid & 2047;
  const float* src = (tens ? y : x) + (size_t)row * HW;
  float s = 0.f, s2 = 0.f;
  for (int j = threadIdx.x; j < HW / 4; j += 256) {
    float4 v = ((const float4*)src)[j];
    s += (v.x + v.y) + (v.z + v.w);
    s2 += (v.x * v.x + v.y * v.y) + (v.z * v.z + v.w * v.w);
  }
  #pragma unroll
  for (int o = 32; o; o >>= 1) { s += __shfl_down(s, o); s2 += __shfl_down(s2, o); }
  __shared__ float rs[8];
  int w = threadIdx.x >> 6;
  if ((threadIdx.x & 63) == 0) { rs[w] = s; rs[4 + w] = s2; }
  __syncthreads();
  if (threadIdx.x == 0) {
    float S = (rs[0] + rs[1]) + (rs[2] + rs[3]);
    float S2 = (rs[4] + rs[5]) + (rs[6] + rs[7]);
    float mean = S * (1.f / HW);
    float var = S2 * (1.f / HW) - mean * mean;
    stats[tens * 4096 + row] = mean;
    stats[tens * 4096 + 2048 + row] = rsqrtf(var + 1e-5f);
  }
}

// ---- transpose f32 [c][i] -> f16 [i][c]; mode0: xnT; mode1: ynT + yH cast ------
__global__ __launch_bounds__(256) void transnorm_k(const float* __restrict__ x,
                                                   const float* __restrict__ y,
                                                   const float* __restrict__ stats,
                                                   unsigned short* __restrict__ xnT,
                                                   unsigned short* __restrict__ ynT,
                                                   unsigned short* __restrict__ yH) {
  __shared__ float tile[64][65];
  __shared__ float ms[64], rsd[64];
  int zi = blockIdx.z;            // [0,8): b = zi>>1, mode = zi&1
  int b = zi >> 1, mode = zi & 1;
  int i0 = blockIdx.x * 64, c0 = blockIdx.y * 64;
  const float* src = mode ? y : x;
  int t = threadIdx.x;
  int c = t >> 2;                 // 0..63
  int isub = (t & 3) << 4;        // 16 i's per thread
  if (t < 64) {
    int srow = (mode ? 4096 : 0) + b * NC + c0 + t;
    ms[t] = stats[srow];
    rsd[t] = stats[srow + 2048];
  }
  const float4* sp = (const float4*)(src + ((size_t)(b * NC + c0 + c)) * HW + i0 + isub);
  #pragma unroll
  for (int k = 0; k < 4; ++k) {
    float4 v = sp[k];
    int ib = isub + k * 4;
    tile[ib + 0][c] = v.x;
    tile[ib + 1][c] = v.y;
    tile[ib + 2][c] = v.z;
    tile[ib + 3][c] = v.w;
    if (mode) {   // straight f16 cast of raw y, [c][i] layout (PV B-operand)
      ush4 yo;
      yo[0] = f2h(v.x); yo[1] = f2h(v.y); yo[2] = f2h(v.z); yo[3] = f2h(v.w);
      *(ush4*)(yH + ((size_t)(b * NC + c0 + c)) * HW + i0 + isub + k * 4) = yo;
    }
  }
  __syncthreads();
  int i = t >> 2;
  int cc = (t & 3) << 4;
  size_t obase = ((size_t)b * HW + i0 + i) * NC + c0 + cc;
  unsigned short* dst = mode ? ynT : xnT;
  #pragma unroll
  for (int h = 0; h < 2; ++h) {
    ush8 o;
    #pragma unroll
    for (int e = 0; e < 8; ++e) {
      int ce = cc + h * 8 + e;
      o[e] = f2h((tile[i][ce] - ms[ce]) * rsd[ce]);
    }
    *(ush8*)(dst + obase + h * 8) = o;
  }
}

// ---- weights -> f16: z=0,1,2 transpose fw,gw,hw ; z=3 straight out_w -----------
__global__ __launch_bounds__(256) void castw_k(const float* __restrict__ fw,
                                               const float* __restrict__ gw,
                                               const float* __restrict__ hw_,
                                               const float* __restrict__ ow,
                                               unsigned short* __restrict__ fwT,
                                               unsigned short* __restrict__ gwT,
                                               unsigned short* __restrict__ hwT,
                                               unsigned short* __restrict__ owB) {
  __shared__ float tile[64][65];
  int which = blockIdx.z;
  const float* src = which == 0 ? fw : which == 1 ? gw : which == 2 ? hw_ : ow;
  unsigned short* dst = which == 0 ? fwT : which == 1 ? gwT : which == 2 ? hwT : owB;
  int r0 = blockIdx.x * 64, c0 = blockIdx.y * 64;
  int t = threadIdx.x;
  int r = t >> 2;
  int csub = (t & 3) << 4;
  const float4* sp = (const float4*)(src + (size_t)(r0 + r) * 512 + c0 + csub);
  if (which == 3) {   // straight cast
    #pragma unroll
    for (int k = 0; k < 4; ++k) {
      float4 v = sp[k];
      ush4 o;
      o[0] = f2h(v.x); o[1] = f2h(v.y); o[2] = f2h(v.z); o[3] = f2h(v.w);
      *(ush4*)(dst + (size_t)(r0 + r) * 512 + c0 + csub + k * 4) = o;
    }
    return;
  }
  #pragma unroll
  for (int k = 0; k < 4; ++k) {
    float4 v = sp[k];
    int cb = csub + k * 4;
    tile[cb + 0][r] = v.x;
    tile[cb + 1][r] = v.y;
    tile[cb + 2][r] = v.z;
    tile[cb + 3][r] = v.w;
  }
  __syncthreads();
  int cw = t >> 2;                 // output row (= source col)
  int rsub = (t & 3) << 4;
  #pragma unroll
  for (int h = 0; h < 2; ++h) {
    ush8 o;
    #pragma unroll
    for (int e = 0; e < 8; ++e) o[e] = f2h(tile[cw][rsub + h * 8 + e]);
    *(ush8*)(dst + (size_t)(c0 + cw) * 512 + r0 + rsub + h * 8) = o;
  }
}

// ---- replicate W2 [512][512] -> W2x2 [512][1024] (k mod 512) -------------------
__global__ __launch_bounds__(256) void repl_k(const unsigned short* __restrict__ W2,
                                              unsigned short* __restrict__ W2x2) {
  int idx = blockIdx.x * 256 + threadIdx.x;   // ush8 index over 512*1024/8
  int o = idx >> 7;
  int k = (idx & 127) * 8;
  ush8 v = *(const ush8*)(W2 + (size_t)o * 512 + (k & 511));
  *(ush8*)(W2x2 + (size_t)o * 1024 + k) = v;
}

// ---- out[row] = sum_k A_f16[row][k] * vec[k], K=512, one wave per row ----------
__global__ __launch_bounds__(256) void dotrows_h(const unsigned short* __restrict__ A,
                                                 const float* __restrict__ vec,
                                                 float* __restrict__ out) {
  int row = blockIdx.x * 4 + (threadIdx.x >> 6);
  int lane = threadIdx.x & 63;
  ush8 a = *(const ush8*)(A + (size_t)row * 512 + lane * 8);
  float s = 0.f;
  #pragma unroll
  for (int e = 0; e < 8; ++e) s += h2f(a[e]) * vec[lane * 8 + e];
  #pragma unroll
  for (int o = 32; o; o >>= 1) s += __shfl_down(s, o);
  if (lane == 0) out[row] = s;
}

// ---- b2[o] = out_b[o] + sum_c out_w_f32[o][c] * h_b[c] -------------------------
__global__ __launch_bounds__(256) void b2_k(const float* __restrict__ Wf,
                                            const float* __restrict__ hb,
                                            const float* __restrict__ ob,
                                            float* __restrict__ out) {
  int row = blockIdx.x * 4 + (threadIdx.x >> 6);
  int lane = threadIdx.x & 63;
  const float4* a = (const float4*)(Wf + (size_t)row * 512) + lane * 2;
  float4 x0 = a[0], x1 = a[1];
  const float4* hv = (const float4*)hb + lane * 2;
  float4 h0 = hv[0], h1 = hv[1];
  float s = x0.x * h0.x + x0.y * h0.y + x0.z * h0.z + x0.w * h0.w
          + x1.x * h1.x + x1.y * h1.y + x1.z * h1.z + x1.w * h1.w;
  #pragma unroll
  for (int o = 32; o; o >>= 1) s += __shfl_down(s, o);
  if (lane == 0) out[row] = ob[row] + s;
}

// ------ row softmax over 4096 f16 IN PLACE (row pitch 4096 f16 = 8KB) -----------
__global__ __launch_bounds__(256) void softmax_h(unsigned short* __restrict__ S) {
  unsigned short* row = S + (size_t)blockIdx.x * HW;
  int t = threadIdx.x;
  ush8 a0 = *(const ush8*)(row + t * 16);
  ush8 a1 = *(const ush8*)(row + t * 16 + 8);
  float v[16];
  #pragma unroll
  for (int e = 0; e < 8; ++e) { v[e] = h2f(a0[e]); v[8 + e] = h2f(a1[e]); }
  float mx = -3.0e38f;
  #pragma unroll
  for (int e = 0; e < 16; ++e) mx = fmaxf(mx, v[e]);
  #pragma unroll
  for (int o = 32; o; o >>= 1) mx = fmaxf(mx, __shfl_down(mx, o));
  __shared__ float red[8];
  int w = t >> 6;
  if ((t & 63) == 0) red[w] = mx;
  __syncthreads();
  mx = fmaxf(fmaxf(red[0], red[1]), fmaxf(red[2], red[3]));
  float sum = 0.f;
  #pragma unroll
  for (int e = 0; e < 16; ++e) { v[e] = __expf(v[e] - mx); sum += v[e]; }
  #pragma unroll
  for (int o = 32; o; o >>= 1) sum += __shfl_down(sum, o);
  if ((t & 63) == 0) red[4 + w] = sum;
  __syncthreads();
  float inv = 1.f / ((red[4] + red[5]) + (red[6] + red[7]));
  ush8 o0, o1;
  #pragma unroll
  for (int e = 0; e < 8; ++e) { o0[e] = f2h(v[e] * inv); o1[e] = f2h(v[8 + e] * inv); }
  *(ush8*)(row + t * 16) = o0;
  *(ush8*)(row + t * 16 + 8) = o1;
}

// --------- NT GEMM (128x128, 2-phase LDS dbuf): small matrices + fallback -------
__global__ __launch_bounds__(256, 2) void gemm_ntp(
    const unsigned short* __restrict__ A, long long sA, int lda,
    const unsigned short* __restrict__ Bm, long long sB, int ldb,
    void* __restrict__ Cp, long long sC, long long sCs, int ldc,
    int K, int out_f32, int ls,
    const float* __restrict__ bias_m, const float* __restrict__ bias_n,
    const float* __restrict__ add_src, long long sAdd,
    const unsigned short* __restrict__ B2, const float* __restrict__ bias_n2,
    int zsw) {
  __shared__ short lsA[2][128 * 64];
  __shared__ short lsB[2][128 * 64];
  const int t = threadIdx.x;
  const int lane = t & 63;
  const int w = t >> 6;
  const int wm = w >> 1, wn = w & 1;
  const long long bz = blockIdx.z;
  if ((int)bz >= zsw) { Bm = B2; bias_n = bias_n2; }
  const long long bg = bz >> ls;
  const int sp = (int)(bz - (bg << ls));
  const long long koff = (long long)sp * K;
  const unsigned short* Ab = A + bz * sA * (ls ? 0 : 1) + (ls ? bg * sA : 0) + koff
                           + (size_t)blockIdx.x * 128 * lda;
  const unsigned short* Bb = Bm + bg * sB + koff + (size_t)blockIdx.y * 128 * ldb;

  f32x4 zero = {0.f, 0.f, 0.f, 0.f};
  f32x4 acc[4][4];
  #pragma unroll
  for (int i = 0; i < 4; ++i)
    #pragma unroll
    for (int j = 0; j < 4; ++j) acc[i][j] = zero;

  const int nkt = K >> 6;

  auto STAGE = [&](int buf, int kt) {
    const int kbase = kt << 6;
    #pragma unroll
    for (int i = 0; i < 4; ++i) {
      int q = t + i * 256;               // chunk id 0..1023
      int r = q >> 3, xx = q & 7;
      int gk = kbase + ((xx ^ (r & 7)) << 3);
      __builtin_amdgcn_global_load_lds((as1_cvp)(const void*)(Ab + (size_t)r * lda + gk),
                                       (as3_vp)(void*)(&lsA[buf][q << 3]), 16, 0, 0);
      __builtin_amdgcn_global_load_lds((as1_cvp)(const void*)(Bb + (size_t)r * ldb + gk),
                                       (as3_vp)(void*)(&lsB[buf][q << 3]), 16, 0, 0);
    }
  };

  STAGE(0, 0);
  __syncthreads();
  int cur = 0;
  for (int kt = 0; kt < nkt; ++kt) {
    if (kt + 1 < nkt) STAGE(cur ^ 1, kt + 1);   // prefetch issued before compute
    #pragma unroll
    for (int ks = 0; ks < 2; ++ks) {
      f16x8 av[4], bv[4];
      const int xl = ks * 4 + (lane >> 4);
      const int rr = lane & 15;
      #pragma unroll
      for (int mb = 0; mb < 4; ++mb) {
        int row = wm * 64 + mb * 16 + rr;
        av[mb] = *(const f16x8*)&lsA[cur][(row << 6) + ((xl ^ (row & 7)) << 3)];
      }
      #pragma unroll
      for (int nb = 0; nb < 4; ++nb) {
        int row = wn * 64 + nb * 16 + rr;
        bv[nb] = *(const f16x8*)&lsB[cur][(row << 6) + ((xl ^ (row & 7)) << 3)];
      }
      __builtin_amdgcn_s_setprio(1);
      #pragma unroll
      for (int mb = 0; mb < 4; ++mb)
        #pragma unroll
        for (int nb = 0; nb < 4; ++nb)
          acc[mb][nb] = __builtin_amdgcn_mfma_f32_16x16x32_f16(av[mb], bv[nb], acc[mb][nb], 0, 0, 0);
      __builtin_amdgcn_s_setprio(0);
    }
    __syncthreads();
    cur ^= 1;
  }

  const int mb0 = blockIdx.x * 128 + wm * 64;
  const int nb0 = blockIdx.y * 128 + wn * 64;
  const int cn = lane & 15;
  const int rq = (lane >> 4) << 2;
  float* cf = (float*)Cp;
  unsigned short* ch = (unsigned short*)Cp;
  #pragma unroll
  for (int mb = 0; mb < 4; ++mb) {
    #pragma unroll
    for (int nb = 0; nb < 4; ++nb) {
      int n = nb0 + nb * 16 + cn;
      float bn = bias_n ? bias_n[n] : 0.f;
      #pragma unroll
      for (int r = 0; r < 4; ++r) {
        int m = mb0 + mb * 16 + rq + r;
        float vv = acc[mb][nb][r] + bn;
        if (bias_m) vv += bias_m[m];
        if (add_src) vv += add_src[bg * sAdd + (size_t)m * ldc + n];
        size_t off = (size_t)(bg * sC) + (size_t)sp * sCs + (size_t)m * ldc + n;
        if (out_f32) cf[off] = vv;
        else ch[off] = f2h(vv);
      }
    }
  }
}

// --------- NT GEMM-8: 256x256 tile, BK=64, 8-phase counted-vmcnt schedule -------
// 512 thr = 8 waves (2M x 4N), per-wave 128x64 out (8 mb x 4 nb fragments).
// LDS: 2 dbuf x 2 M-half x [128][64] for A and B = 128 KB. Tile t uses dbuf t&1.
// Phases 0-3 compute even tile t0 (B front-loaded at p0, A per M-quadrant);
// phases 4-7 compute odd tile t1. Stage schedule (each target region fully
// read before the previous end-of-phase barrier; lands before reuse via the
// counted vmcnt(4) at p3 and p7 -- never 0 in steady state):
//   p0: A(t1) h0+h1      (lsA[1] free since prev p7; landed by p3 vmcnt(4))
//   p1: B(t0+2) h0       (lsB[0] free since p0;     landed by p7 vmcnt(4))
//   p2: B(t0+2) h1
//   p4: A(t0+2) h0       (lsA[0] free since p3;     landed by p7 vmcnt(4))
//   p5: A(t0+2) h1
//   p6: B(t1+2) h0       (lsB[1] free since p4;     landed by next p3 vmcnt)
//   p7: B(t1+2) h1
// Per phase: ds_reads -> stage -> s_barrier -> lgkmcnt(0)+sched_barrier(0)
// (rule #18) -> setprio(1) 16 MFMA setprio(0) -> [vmcnt(4) at p3/p7] -> barrier.
// Requires nkt even (all call sites: 8/16/32).
__global__ __launch_bounds__(512, 1) void gemm_nt8(
    const unsigned short* __restrict__ A, long long sA, int lda,
    const unsigned short* __restrict__ Bm, long long sB, int ldb,
    void* __restrict__ Cp, long long sC, long long sCs, int ldc,
    int K, int out_f32, int ls,
    const float* __restrict__ bias_m,
    const float* __restrict__ bias_n, long long sBn,
    const float* __restrict__ add_src, long long sAdd) {
  __shared__ short lsA[2][2][128 * 64];   // [dbuf][half] 64 KB
  __shared__ short lsB[2][2][128 * 64];   // 64 KB
  const int t = threadIdx.x;
  const int lane = t & 63;
  const int w = t >> 6;                   // 0..7
  const int wm = w >> 2, wn = w & 3;      // 2M x 4N
  const long long bz = blockIdx.z;
  const long long bg = bz >> ls;
  const int sp = (int)(bz - (bg << ls));
  const long long koff = (long long)sp * K;
  const unsigned short* Ab = A + bg * sA + koff + (size_t)blockIdx.x * 256 * lda;
  const unsigned short* Bb = Bm + bg * sB + koff + (size_t)blockIdx.y * 256 * ldb;

  f32x4 zero = {0.f, 0.f, 0.f, 0.f};
  f32x4 acc[8][4];
  #pragma unroll
  for (int i = 0; i < 8; ++i)
    #pragma unroll
    for (int j = 0; j < 4; ++j) acc[i][j] = zero;

  const int rr = lane & 15;
  const int xl = lane >> 4;
  const int nkt = K >> 6;

  auto STAGE_A = [&](int kt, int hh) {    // one half-tile: 2 loads/thread
    const int slot = kt & 1, kbase = kt << 6;
    #pragma unroll
    for (int i2 = 0; i2 < 2; ++i2) {
      int q = t + i2 * 512;               // 0..1023 over [128 rows][8 chunks]
      int r = q >> 3, xx = q & 7;
      int gk = kbase + ((xx ^ (r & 7)) << 3);
      __builtin_amdgcn_global_load_lds(
          (as1_cvp)(const void*)(Ab + (size_t)(hh * 128 + r) * lda + gk),
          (as3_vp)(void*)(&lsA[slot][hh][q << 3]), 16, 0, 0);
    }
  };
  auto STAGE_B = [&](int kt, int hh) {
    const int slot = kt & 1, kbase = kt << 6;
    #pragma unroll
    for (int i2 = 0; i2 < 2; ++i2) {
      int q = t + i2 * 512;
      int r = q >> 3, xx = q & 7;
      int gk = kbase + ((xx ^ (r & 7)) << 3);
      __builtin_amdgcn_global_load_lds(
          (as1_cvp)(const void*)(Bb + (size_t)(hh * 128 + r) * ldb + gk),
          (as3_vp)(void*)(&lsB[slot][hh][q << 3]), 16, 0, 0);
    }
  };

  f16x8 bv[4][2];                         // wave's full B tile (persists 4 phases)
  f16x8 av[2][2];                         // current M-quadrant of A
  auto READ_B = [&](int slot) {
    #pragma unroll
    for (int nb = 0; nb < 4; ++nb)
      #pragma unroll
      for (int ks = 0; ks < 2; ++ks) {
        int lr = (wn & 1) * 64 + nb * 16 + rr;   // local row in half (wn>>1)
        int cb = ks * 4 + xl;
        bv[nb][ks] = *(const f16x8*)&lsB[slot][wn >> 1][(lr << 6) + ((cb ^ (lr & 7)) << 3)];
      }
  };
  auto READ_A = [&](int slot, int p) {
    #pragma unroll
    for (int j = 0; j < 2; ++j)
      #pragma unroll
      for (int ks = 0; ks < 2; ++ks) {
        int lr = (2 * p + j) * 16 + rr;           // local row in half wm
        int cb = ks * 4 + xl;
        av[j][ks] = *(const f16x8*)&lsA[slot][wm][(lr << 6) + ((cb ^ (lr & 7)) << 3)];
      }
  };
  auto MFMA16 = [&](int p) {
    __builtin_amdgcn_s_setprio(1);
    #pragma unroll
    for (int j = 0; j < 2; ++j)
      #pragma unroll
      for (int nb = 0; nb < 4; ++nb)
        #pragma unroll
        for (int ks = 0; ks < 2; ++ks)
          acc[2 * p + j][nb] = __builtin_amdgcn_mfma_f32_16x16x32_f16(
              av[j][ks], bv[nb][ks], acc[2 * p + j][nb], 0, 0, 0);
    __builtin_amdgcn_s_setprio(0);
  };

  // prologue: tile 0 (A+B) then tile 1's B; wait tile 0 landed (4 B1-loads fly)
  STAGE_A(0, 0); STAGE_A(0, 1); STAGE_B(0, 0); STAGE_B(0, 1);
  if (nkt > 1) {
    STAGE_B(1, 0); STAGE_B(1, 1);
    asm volatile("s_waitcnt vmcnt(4)" ::: "memory");
  } else {
    asm volatile("s_waitcnt vmcnt(0)" ::: "memory");
  }
  __builtin_amdgcn_s_barrier();

  const int niter = nkt >> 1;
  for (int it = 0; it < niter; ++it) {
    const int t0 = 2 * it, t1 = 2 * it + 1;
    // ---- phases 0-3: tile t0 from dbuf 0 ----
    #pragma unroll
    for (int p = 0; p < 4; ++p) {
      if (p == 0) READ_B(0);
      READ_A(0, p);
      if (p == 0)      { STAGE_A(t1, 0); STAGE_A(t1, 1); }
      else if (p == 1) { if (t0 + 2 < nkt) STAGE_B(t0 + 2, 0); }
      else if (p == 2) { if (t0 + 2 < nkt) STAGE_B(t0 + 2, 1); }
      __builtin_amdgcn_s_barrier();
      asm volatile("s_waitcnt lgkmcnt(0)" ::: "memory");
      __builtin_amdgcn_sched_barrier(0);
      MFMA16(p);
      if (p == 3) asm volatile("s_waitcnt vmcnt(4)" ::: "memory");
      __builtin_amdgcn_s_barrier();
    }
    // ---- phases 4-7: tile t1 from dbuf 1 ----
    #pragma unroll
    for (int p = 0; p < 4; ++p) {
      if (p == 0) READ_B(1);
      READ_A(1, p);
      if (p == 0)      { if (t0 + 2 < nkt) STAGE_A(t0 + 2, 0); }
      else if (p == 1) { if (t0 + 2 < nkt) STAGE_A(t0 + 2, 1); }
      else if (p == 2) { if (t1 + 2 < nkt) STAGE_B(t1 + 2, 0); }
      else             { if (t1 + 2 < nkt) STAGE_B(t1 + 2, 1); }
      __builtin_amdgcn_s_barrier();
      asm volatile("s_waitcnt lgkmcnt(0)" ::: "memory");
      __builtin_amdgcn_sched_barrier(0);
      MFMA16(p);
      if (p == 3) asm volatile("s_waitcnt vmcnt(4)" ::: "memory");
      __builtin_amdgcn_s_barrier();
    }
  }
  asm volatile("s_waitcnt vmcnt(0)" ::: "memory");  // drain before endpgm

  const int mb0 = blockIdx.x * 256 + wm * 128;
  const int nb0 = blockIdx.y * 256 + wn * 64;
  const int cn = lane & 15;
  const int rq = (lane >> 4) << 2;
  float* cf = (float*)Cp;
  unsigned short* ch = (unsigned short*)Cp;
  #pragma unroll
  for (int mb = 0; mb < 8; ++mb) {
    #pragma unroll
    for (int nb = 0; nb < 4; ++nb) {
      int n = nb0 + nb * 16 + cn;
      float bn = bias_n ? bias_n[bg * sBn + n] : 0.f;
      #pragma unroll
      for (int r = 0; r < 4; ++r) {
        int m = mb0 + mb * 16 + rq + r;
        float vv = acc[mb][nb][r] + bn;
        if (bias_m) vv += bias_m[m];
        if (add_src) vv += add_src[bg * sAdd + (size_t)m * ldc + n];
        size_t off = (size_t)(bg * sC) + (size_t)sp * sCs + (size_t)m * ldc + n;
        if (out_f32) cf[off] = vv;
        else ch[off] = f2h(vv);
      }
    }
  }
}

extern "C" void kernel_launch(void* const* d_in, const int* in_sizes, int n_in,
                              void* d_out, int out_size, void* d_ws, size_t ws_size,
                              hipStream_t stream) {
  const float* x = (const float*)d_in[0];
  const float* y = (const float*)d_in[1];
  const float* f_w = (const float*)d_in[2];
  const float* f_b = (const float*)d_in[3];
  const float* g_w = (const float*)d_in[4];
  const float* g_b = (const float*)d_in[5];  // dropped: row-constant shift, softmax-exact
  const float* h_w = (const float*)d_in[6];
  const float* h_b = (const float*)d_in[7];
  const float* out_w = (const float*)d_in[8];
  const float* out_b = (const float*)d_in[9];
  float* out = (float*)d_out;
  (void)g_b;

  char* ws = (char*)d_ws;
  size_t off = 0;
  auto alloc = [&](size_t bytes) -> char* {
    char* p = ws + off;
    off += (bytes + 255) & ~(size_t)255;
    return p;
  };
  const size_t TN = (size_t)NB * HW * NC;  // elems per [B][HW][C] buf
  const size_t WN = (size_t)512 * 512;
  float* stats = (float*)alloc(8192 * sizeof(float));
  unsigned short* fwT = (unsigned short*)alloc(WN * 2);
  unsigned short* gwT = (unsigned short*)alloc(WN * 2);
  unsigned short* hwT = (unsigned short*)alloc(WN * 2);
  unsigned short* owB = (unsigned short*)alloc(WN * 2);
  unsigned short* W1T = (unsigned short*)alloc(WN * 2);
  unsigned short* W2 = (unsigned short*)alloc(WN * 2);
  unsigned short* W2x2 = (unsigned short*)alloc((size_t)512 * 1024 * 2);
  float* vv = (float*)alloc(512 * 4);
  float* b2 = (float*)alloc(512 * 4);
  float* wj = (float*)alloc((size_t)NB * HW * 4);
  unsigned short* xnT = (unsigned short*)alloc(TN * 2);
  unsigned short* ynT = (unsigned short*)alloc(TN * 2);
  unsigned short* yH = (unsigned short*)alloc(TN * 2);
  unsigned short* fB = (unsigned short*)alloc(TN * 2);    // F2
  unsigned short* Zp = (unsigned short*)alloc((size_t)NB * HW * 1024 * 2);  // 32MB
  size_t remain = ws_size > off ? ws_size - off : 0;
  // per-batch attention footprint: S f16 only (32MB)
  const size_t SB = (size_t)HW * HW * 2;
  int G, R = HW;
  if (remain >= 4 * SB)      { G = 4; }
  else if (remain >= 2 * SB) { G = 2; }
  else if (remain >= SB)     { G = 1; }
  else {
    G = 1;
    while (R > 128 && (size_t)R * HW * 2 > remain) R >>= 1;
  }
  unsigned short* Sh = (unsigned short*)alloc((size_t)G * R * HW * 2);
  if (off > ws_size) return;  // scratch too small; cannot run

  const long long PS = (long long)HW * NC;  // per-batch stride (elements)
  const int BIG = 1 << 30;

  castw_k<<<dim3(8, 8, 4), dim3(256), 0, stream>>>(f_w, g_w, h_w, out_w,
                                                   fwT, gwT, hwT, owB);
  moments_k<<<dim3(4096), dim3(256), 0, stream>>>(x, y, stats);
  transnorm_k<<<dim3(64, 8, 8), dim3(256), 0, stream>>>(x, y, stats, xnT, ynT, yH);

  // v[c] = sum_o Gw[o][c] f_b[o] ; b2[o] = out_b[o] + sum_c OutW[o][c] h_b[c]
  dotrows_h<<<dim3(128), dim3(256), 0, stream>>>(gwT, f_b, vv);
  b2_k<<<dim3(128), dim3(256), 0, stream>>>(out_w, h_b, out_b, b2);
  // W1T[c2][c1] = sum_o Gw[o][c2] Fw[o][c1]   (= (Fw^T Gw)^T, F2's B-operand)
  gemm_ntp<<<dim3(4, 4, 1), dim3(256), 0, stream>>>(
      gwT, 0, 512, fwT, 0, 512, W1T, 0, 0, 512, 512, 0, 0,
      nullptr, nullptr, nullptr, 0, nullptr, nullptr, BIG);
  // W2[o][c'] = sum_c OutW[o][c] Hw[c][c']
  gemm_ntp<<<dim3(4, 4, 1), dim3(256), 0, stream>>>(
      owB, 0, 512, hwT, 0, 512, W2, 0, 0, 512, 512, 0, 0,
      nullptr, nullptr, nullptr, 0, nullptr, nullptr, BIG);
  repl_k<<<dim3(256), dim3(256), 0, stream>>>(W2, W2x2);
  // w[b][j] = Yn[b][j] . v
  dotrows_h<<<dim3(NB * HW / 4), dim3(256), 0, stream>>>(ynT, vv, wj);
  // F2[b][i][c'] = Xn . W1   (8-phase, grid 16x2x4)
  gemm_nt8<<<dim3(16, 2, NB), dim3(512), 0, stream>>>(
      xnT, PS, NC, W1T, 0, NC, fB, PS, 0, NC, NC, 0, 0,
      nullptr, nullptr, 0, nullptr, 0);

  for (int b0 = 0; b0 < NB; b0 += G) {
    for (int r0 = 0; r0 < HW; r0 += R) {
      if (R >= 256) {
        // E[bg][i][j] = F2[i][:] . Yn[j][:] + w[bg][j]  -> f16, pitch HW
        gemm_nt8<<<dim3(R / 256, HW / 256, G), dim3(512), 0, stream>>>(
            fB + ((size_t)b0 * HW + r0) * NC, PS, NC,
            ynT + (size_t)b0 * PS, PS, NC,
            Sh, (long long)R * HW, 0, HW, NC, 0, 0,
            nullptr, wj + (size_t)b0 * HW, HW, nullptr, 0);
        softmax_h<<<dim3(G * R), dim3(256), 0, stream>>>(Sh);
        // Zp[i][sp*512+c'] = P[i][sp-half] . y[c'][sp-half]  (f16, K-interleaved)
        gemm_nt8<<<dim3(R / 256, NC / 256, G * 2), dim3(512), 0, stream>>>(
            Sh, (long long)R * HW, HW,
            yH + (size_t)b0 * NC * HW, (long long)NC * HW, HW,
            Zp + ((size_t)b0 * HW + r0) * 1024, (long long)R * 1024, 512, 1024,
            HW / 2, 0, 1,
            nullptr, nullptr, 0, nullptr, 0);
      } else {
        gemm_ntp<<<dim3(R / 128, 32, G), dim3(256), 0, stream>>>(
            fB + ((size_t)b0 * HW + r0) * NC, PS, NC,
            ynT + (size_t)b0 * PS, PS, NC,
            Sh, (long long)R * HW, 0, HW, NC, 0, 0,
            nullptr, wj + (size_t)b0 * HW, nullptr, 0, nullptr, nullptr, BIG);
        softmax_h<<<dim3(G * R), dim3(256), 0, stream>>>(Sh);
        gemm_ntp<<<dim3(R / 128, 4, G * 2), dim3(256), 0, stream>>>(
            Sh, (long long)R * HW, HW,
            yH + (size_t)b0 * NC * HW, (long long)NC * HW, HW,
            Zp + ((size_t)b0 * HW + r0) * 1024, (long long)R * 1024, 512, 1024,
            HW / 2, 0, 1,
            nullptr, nullptr, nullptr, 0, nullptr, nullptr, BIG);
      }
    }
  }
  // out[b][o][i] = W2x2 . Zp^T + b2[o] + x   (f32 out; K=1024 folds the 2 splits)
  gemm_nt8<<<dim3(2, 16, NB), dim3(512), 0, stream>>>(
      W2x2, 0, 1024, Zp, (long long)HW * 1024, 1024,
      out, (long long)NC * HW, 0, HW, 1024, 1, 0,
      b2, nullptr, 0, x, (long long)NC * HW);
}

// Round 16
// 390.976 us; speedup vs baseline: 1.1638x; 1.1638x over previous
//
#include <hip/hip_runtime.h>
#include <stdint.h>

#define HW 4096
#define NC 512
#define NB 4

typedef __attribute__((ext_vector_type(8))) _Float16 f16x8;
typedef __attribute__((ext_vector_type(4))) float f32x4;
typedef __attribute__((ext_vector_type(4))) unsigned short ush4;
typedef __attribute__((ext_vector_type(8))) unsigned short ush8;

typedef __attribute__((address_space(1))) const void* as1_cvp;
typedef __attribute__((address_space(3))) void* as3_vp;

__device__ __forceinline__ unsigned short f2h(float f) {
  union { _Float16 h; unsigned short u; } c;
  c.h = (_Float16)f;           // hardware v_cvt_f16_f32, RNE
  return c.u;
}
__device__ __forceinline__ float h2f(unsigned short u) {
  union { unsigned short u; _Float16 h; } c;
  c.u = u;
  return (float)c.h;
}

// ---------------- moments: per-(b,c) mean/rstd over 4096 spatial elems ----------
__global__ __launch_bounds__(256) void moments_k(const float* __restrict__ x,
                                                 const float* __restrict__ y,
                                                 float* __restrict__ stats) {
  int bid = blockIdx.x;          // 0..4095 : [tensor(2)][b*C+c (2048)]
  int tens = bid >> 11;
  int row = bid & 2047;
  const float* src = (tens ? y : x) + (size_t)row * HW;
  float s = 0.f, s2 = 0.f;
  for (int j = threadIdx.x; j < HW / 4; j += 256) {
    float4 v = ((const float4*)src)[j];
    s += (v.x + v.y) + (v.z + v.w);
    s2 += (v.x * v.x + v.y * v.y) + (v.z * v.z + v.w * v.w);
  }
  #pragma unroll
  for (int o = 32; o; o >>= 1) { s += __shfl_down(s, o); s2 += __shfl_down(s2, o); }
  __shared__ float rs[8];
  int w = threadIdx.x >> 6;
  if ((threadIdx.x & 63) == 0) { rs[w] = s; rs[4 + w] = s2; }
  __syncthreads();
  if (threadIdx.x == 0) {
    float S = (rs[0] + rs[1]) + (rs[2] + rs[3]);
    float S2 = (rs[4] + rs[5]) + (rs[6] + rs[7]);
    float mean = S * (1.f / HW);
    float var = S2 * (1.f / HW) - mean * mean;
    stats[tens * 4096 + row] = mean;
    stats[tens * 4096 + 2048 + row] = rsqrtf(var + 1e-5f);
  }
}

// ---- transpose f32 [c][i] -> f16 [i][c]; mode0: xnT; mode1: ynT + yH cast ------
__global__ __launch_bounds__(256) void transnorm_k(const float* __restrict__ x,
                                                   const float* __restrict__ y,
                                                   const float* __restrict__ stats,
                                                   unsigned short* __restrict__ xnT,
                                                   unsigned short* __restrict__ ynT,
                                                   unsigned short* __restrict__ yH) {
  __shared__ float tile[64][65];
  __shared__ float ms[64], rsd[64];
  int zi = blockIdx.z;            // [0,8): b = zi>>1, mode = zi&1
  int b = zi >> 1, mode = zi & 1;
  int i0 = blockIdx.x * 64, c0 = blockIdx.y * 64;
  const float* src = mode ? y : x;
  int t = threadIdx.x;
  int c = t >> 2;                 // 0..63
  int isub = (t & 3) << 4;        // 16 i's per thread
  if (t < 64) {
    int srow = (mode ? 4096 : 0) + b * NC + c0 + t;
    ms[t] = stats[srow];
    rsd[t] = stats[srow + 2048];
  }
  const float4* sp = (const float4*)(src + ((size_t)(b * NC + c0 + c)) * HW + i0 + isub);
  #pragma unroll
  for (int k = 0; k < 4; ++k) {
    float4 v = sp[k];
    int ib = isub + k * 4;
    tile[ib + 0][c] = v.x;
    tile[ib + 1][c] = v.y;
    tile[ib + 2][c] = v.z;
    tile[ib + 3][c] = v.w;
    if (mode) {   // straight f16 cast of raw y, [c][i] layout (PV B-operand)
      ush4 yo;
      yo[0] = f2h(v.x); yo[1] = f2h(v.y); yo[2] = f2h(v.z); yo[3] = f2h(v.w);
      *(ush4*)(yH + ((size_t)(b * NC + c0 + c)) * HW + i0 + isub + k * 4) = yo;
    }
  }
  __syncthreads();
  int i = t >> 2;
  int cc = (t & 3) << 4;
  size_t obase = ((size_t)b * HW + i0 + i) * NC + c0 + cc;
  unsigned short* dst = mode ? ynT : xnT;
  #pragma unroll
  for (int h = 0; h < 2; ++h) {
    ush8 o;
    #pragma unroll
    for (int e = 0; e < 8; ++e) {
      int ce = cc + h * 8 + e;
      o[e] = f2h((tile[i][ce] - ms[ce]) * rsd[ce]);
    }
    *(ush8*)(dst + obase + h * 8) = o;
  }
}

// ---- weights -> f16: z=0,1,2 transpose fw,gw,hw ; z=3 straight out_w -----------
__global__ __launch_bounds__(256) void castw_k(const float* __restrict__ fw,
                                               const float* __restrict__ gw,
                                               const float* __restrict__ hw_,
                                               const float* __restrict__ ow,
                                               unsigned short* __restrict__ fwT,
                                               unsigned short* __restrict__ gwT,
                                               unsigned short* __restrict__ hwT,
                                               unsigned short* __restrict__ owB) {
  __shared__ float tile[64][65];
  int which = blockIdx.z;
  const float* src = which == 0 ? fw : which == 1 ? gw : which == 2 ? hw_ : ow;
  unsigned short* dst = which == 0 ? fwT : which == 1 ? gwT : which == 2 ? hwT : owB;
  int r0 = blockIdx.x * 64, c0 = blockIdx.y * 64;
  int t = threadIdx.x;
  int r = t >> 2;
  int csub = (t & 3) << 4;
  const float4* sp = (const float4*)(src + (size_t)(r0 + r) * 512 + c0 + csub);
  if (which == 3) {   // straight cast
    #pragma unroll
    for (int k = 0; k < 4; ++k) {
      float4 v = sp[k];
      ush4 o;
      o[0] = f2h(v.x); o[1] = f2h(v.y); o[2] = f2h(v.z); o[3] = f2h(v.w);
      *(ush4*)(dst + (size_t)(r0 + r) * 512 + c0 + csub + k * 4) = o;
    }
    return;
  }
  #pragma unroll
  for (int k = 0; k < 4; ++k) {
    float4 v = sp[k];
    int cb = csub + k * 4;
    tile[cb + 0][r] = v.x;
    tile[cb + 1][r] = v.y;
    tile[cb + 2][r] = v.z;
    tile[cb + 3][r] = v.w;
  }
  __syncthreads();
  int cw = t >> 2;                 // output row (= source col)
  int rsub = (t & 3) << 4;
  #pragma unroll
  for (int h = 0; h < 2; ++h) {
    ush8 o;
    #pragma unroll
    for (int e = 0; e < 8; ++e) o[e] = f2h(tile[cw][rsub + h * 8 + e]);
    *(ush8*)(dst + (size_t)(c0 + cw) * 512 + r0 + rsub + h * 8) = o;
  }
}

// ---- replicate W2 [512][512] -> W2x2 [512][1024] (k mod 512) -------------------
__global__ __launch_bounds__(256) void repl_k(const unsigned short* __restrict__ W2,
                                              unsigned short* __restrict__ W2x2) {
  int idx = blockIdx.x * 256 + threadIdx.x;   // ush8 index over 512*1024/8
  int o = idx >> 7;
  int k = (idx & 127) * 8;
  ush8 v = *(const ush8*)(W2 + (size_t)o * 512 + (k & 511));
  *(ush8*)(W2x2 + (size_t)o * 1024 + k) = v;
}

// ---- out[row] = sum_k A_f16[row][k] * vec[k], K=512, one wave per row ----------
__global__ __launch_bounds__(256) void dotrows_h(const unsigned short* __restrict__ A,
                                                 const float* __restrict__ vec,
                                                 float* __restrict__ out) {
  int row = blockIdx.x * 4 + (threadIdx.x >> 6);
  int lane = threadIdx.x & 63;
  ush8 a = *(const ush8*)(A + (size_t)row * 512 + lane * 8);
  float s = 0.f;
  #pragma unroll
  for (int e = 0; e < 8; ++e) s += h2f(a[e]) * vec[lane * 8 + e];
  #pragma unroll
  for (int o = 32; o; o >>= 1) s += __shfl_down(s, o);
  if (lane == 0) out[row] = s;
}

// ---- b2[o] = out_b[o] + sum_c out_w_f32[o][c] * h_b[c] -------------------------
__global__ __launch_bounds__(256) void b2_k(const float* __restrict__ Wf,
                                            const float* __restrict__ hb,
                                            const float* __restrict__ ob,
                                            float* __restrict__ out) {
  int row = blockIdx.x * 4 + (threadIdx.x >> 6);
  int lane = threadIdx.x & 63;
  const float4* a = (const float4*)(Wf + (size_t)row * 512) + lane * 2;
  float4 x0 = a[0], x1 = a[1];
  const float4* hv = (const float4*)hb + lane * 2;
  float4 h0 = hv[0], h1 = hv[1];
  float s = x0.x * h0.x + x0.y * h0.y + x0.z * h0.z + x0.w * h0.w
          + x1.x * h1.x + x1.y * h1.y + x1.z * h1.z + x1.w * h1.w;
  #pragma unroll
  for (int o = 32; o; o >>= 1) s += __shfl_down(s, o);
  if (lane == 0) out[row] = ob[row] + s;
}

// ------ row softmax over 4096 f16 IN PLACE (row pitch 4096 f16 = 8KB) -----------
__global__ __launch_bounds__(256) void softmax_h(unsigned short* __restrict__ S) {
  unsigned short* row = S + (size_t)blockIdx.x * HW;
  int t = threadIdx.x;
  ush8 a0 = *(const ush8*)(row + t * 16);
  ush8 a1 = *(const ush8*)(row + t * 16 + 8);
  float v[16];
  #pragma unroll
  for (int e = 0; e < 8; ++e) { v[e] = h2f(a0[e]); v[8 + e] = h2f(a1[e]); }
  float mx = -3.0e38f;
  #pragma unroll
  for (int e = 0; e < 16; ++e) mx = fmaxf(mx, v[e]);
  #pragma unroll
  for (int o = 32; o; o >>= 1) mx = fmaxf(mx, __shfl_down(mx, o));
  __shared__ float red[8];
  int w = t >> 6;
  if ((t & 63) == 0) red[w] = mx;
  __syncthreads();
  mx = fmaxf(fmaxf(red[0], red[1]), fmaxf(red[2], red[3]));
  float sum = 0.f;
  #pragma unroll
  for (int e = 0; e < 16; ++e) { v[e] = __expf(v[e] - mx); sum += v[e]; }
  #pragma unroll
  for (int o = 32; o; o >>= 1) sum += __shfl_down(sum, o);
  if ((t & 63) == 0) red[4 + w] = sum;
  __syncthreads();
  float inv = 1.f / ((red[4] + red[5]) + (red[6] + red[7]));
  ush8 o0, o1;
  #pragma unroll
  for (int e = 0; e < 8; ++e) { o0[e] = f2h(v[e] * inv); o1[e] = f2h(v[8 + e] * inv); }
  *(ush8*)(row + t * 16) = o0;
  *(ush8*)(row + t * 16 + 8) = o1;
}

// --------- NT GEMM (128x128, 2-phase LDS dbuf): C[m][n] = sum_k A[m][k]*B[n][k] -
// Split-K: bz = bg*2^ls + sp; koff = sp*K; C off = bg*sC + sp*sCs + m*ldc + n.
// zsw: blocks with blockIdx.z >= zsw switch B operand/bias (fusion hook).
__global__ __launch_bounds__(256, 2) void gemm_ntp(
    const unsigned short* __restrict__ A, long long sA, int lda,
    const unsigned short* __restrict__ Bm, long long sB, int ldb,
    void* __restrict__ Cp, long long sC, long long sCs, int ldc,
    int K, int out_f32, int ls,
    const float* __restrict__ bias_m, const float* __restrict__ bias_n,
    const float* __restrict__ add_src, long long sAdd,
    const unsigned short* __restrict__ B2, const float* __restrict__ bias_n2,
    int zsw) {
  __shared__ short lsA[2][128 * 64];
  __shared__ short lsB[2][128 * 64];
  const int t = threadIdx.x;
  const int lane = t & 63;
  const int w = t >> 6;
  const int wm = w >> 1, wn = w & 1;
  const long long bz = blockIdx.z;
  if ((int)bz >= zsw) { Bm = B2; bias_n = bias_n2; }
  const long long bg = bz >> ls;
  const int sp = (int)(bz - (bg << ls));
  const long long koff = (long long)sp * K;
  const unsigned short* Ab = A + bz * sA * (ls ? 0 : 1) + (ls ? bg * sA : 0) + koff
                           + (size_t)blockIdx.x * 128 * lda;
  const unsigned short* Bb = Bm + bg * sB + koff + (size_t)blockIdx.y * 128 * ldb;

  f32x4 zero = {0.f, 0.f, 0.f, 0.f};
  f32x4 acc[4][4];
  #pragma unroll
  for (int i = 0; i < 4; ++i)
    #pragma unroll
    for (int j = 0; j < 4; ++j) acc[i][j] = zero;

  const int nkt = K >> 6;

  auto STAGE = [&](int buf, int kt) {
    const int kbase = kt << 6;
    #pragma unroll
    for (int i = 0; i < 4; ++i) {
      int q = t + i * 256;               // chunk id 0..1023
      int r = q >> 3, xx = q & 7;
      int gk = kbase + ((xx ^ (r & 7)) << 3);
      __builtin_amdgcn_global_load_lds((as1_cvp)(const void*)(Ab + (size_t)r * lda + gk),
                                       (as3_vp)(void*)(&lsA[buf][q << 3]), 16, 0, 0);
      __builtin_amdgcn_global_load_lds((as1_cvp)(const void*)(Bb + (size_t)r * ldb + gk),
                                       (as3_vp)(void*)(&lsB[buf][q << 3]), 16, 0, 0);
    }
  };

  STAGE(0, 0);
  __syncthreads();
  int cur = 0;
  for (int kt = 0; kt < nkt; ++kt) {
    if (kt + 1 < nkt) STAGE(cur ^ 1, kt + 1);   // prefetch issued before compute
    #pragma unroll
    for (int ks = 0; ks < 2; ++ks) {
      f16x8 av[4], bv[4];
      const int xl = ks * 4 + (lane >> 4);
      const int rr = lane & 15;
      #pragma unroll
      for (int mb = 0; mb < 4; ++mb) {
        int row = wm * 64 + mb * 16 + rr;
        av[mb] = *(const f16x8*)&lsA[cur][(row << 6) + ((xl ^ (row & 7)) << 3)];
      }
      #pragma unroll
      for (int nb = 0; nb < 4; ++nb) {
        int row = wn * 64 + nb * 16 + rr;
        bv[nb] = *(const f16x8*)&lsB[cur][(row << 6) + ((xl ^ (row & 7)) << 3)];
      }
      __builtin_amdgcn_s_setprio(1);
      #pragma unroll
      for (int mb = 0; mb < 4; ++mb)
        #pragma unroll
        for (int nb = 0; nb < 4; ++nb)
          acc[mb][nb] = __builtin_amdgcn_mfma_f32_16x16x32_f16(av[mb], bv[nb], acc[mb][nb], 0, 0, 0);
      __builtin_amdgcn_s_setprio(0);
    }
    __syncthreads();
    cur ^= 1;
  }

  const int mb0 = blockIdx.x * 128 + wm * 64;
  const int nb0 = blockIdx.y * 128 + wn * 64;
  const int cn = lane & 15;
  const int rq = (lane >> 4) << 2;
  float* cf = (float*)Cp;
  unsigned short* ch = (unsigned short*)Cp;
  #pragma unroll
  for (int mb = 0; mb < 4; ++mb) {
    #pragma unroll
    for (int nb = 0; nb < 4; ++nb) {
      int n = nb0 + nb * 16 + cn;
      float bn = bias_n ? bias_n[n] : 0.f;
      #pragma unroll
      for (int r = 0; r < 4; ++r) {
        int m = mb0 + mb * 16 + rq + r;
        float vv = acc[mb][nb][r] + bn;
        if (bias_m) vv += bias_m[m];
        if (add_src) vv += add_src[bg * sAdd + (size_t)m * ldc + n];
        size_t off = (size_t)(bg * sC) + (size_t)sp * sCs + (size_t)m * ldc + n;
        if (out_f32) cf[off] = vv;
        else ch[off] = f2h(vv);
      }
    }
  }
}

// --------- NT GEMM2 (256x256, 2-phase dbuf): energy only (per-z bias_n) ---------
__global__ __launch_bounds__(512, 2) void gemm_nt2(
    const unsigned short* __restrict__ A, long long sA, int lda,
    const unsigned short* __restrict__ Bm, long long sB, int ldb,
    void* __restrict__ Cp, long long sC, int ldc,
    int K, int out_f32,
    const float* __restrict__ bias_n, long long sBn) {
  __shared__ short lsA[2][256 * 64];
  __shared__ short lsB[2][256 * 64];
  const int t = threadIdx.x;
  const int lane = t & 63;
  const int w = t >> 6;          // 0..7
  const int wm = w >> 2, wn = w & 3;
  const long long bz = blockIdx.z;
  const unsigned short* Ab = A + bz * sA + (size_t)blockIdx.x * 256 * lda;
  const unsigned short* Bb = Bm + bz * sB + (size_t)blockIdx.y * 256 * ldb;

  f32x4 zero = {0.f, 0.f, 0.f, 0.f};
  f32x4 acc[8][4];
  #pragma unroll
  for (int i = 0; i < 8; ++i)
    #pragma unroll
    for (int j = 0; j < 4; ++j) acc[i][j] = zero;

  const int rr = lane & 15;
  const int xl = lane >> 4;
  const int nkt = K >> 6;

  auto STAGE = [&](int buf, int kt) {
    const int kbase = kt << 6;
    #pragma unroll
    for (int i = 0; i < 4; ++i) {
      int q = t + i * 512;               // chunk id 0..2047
      int r = q >> 3, xx = q & 7;
      int gk = kbase + ((xx ^ (r & 7)) << 3);
      __builtin_amdgcn_global_load_lds((as1_cvp)(const void*)(Ab + (size_t)r * lda + gk),
                                       (as3_vp)(void*)(&lsA[buf][q << 3]), 16, 0, 0);
      __builtin_amdgcn_global_load_lds((as1_cvp)(const void*)(Bb + (size_t)r * ldb + gk),
                                       (as3_vp)(void*)(&lsB[buf][q << 3]), 16, 0, 0);
    }
  };

  STAGE(0, 0);
  __syncthreads();
  int cur = 0;
  for (int kt = 0; kt < nkt; ++kt) {
    if (kt + 1 < nkt) STAGE(cur ^ 1, kt + 1);
    #pragma unroll
    for (int ks = 0; ks < 2; ++ks) {
      f16x8 av[8], bv[4];
      const int cb = ks * 4 + xl;
      #pragma unroll
      for (int mb = 0; mb < 8; ++mb) {
        int row = wm * 128 + mb * 16 + rr;
        av[mb] = *(const f16x8*)&lsA[cur][(row << 6) + ((cb ^ (row & 7)) << 3)];
      }
      #pragma unroll
      for (int nb = 0; nb < 4; ++nb) {
        int row = wn * 64 + nb * 16 + rr;
        bv[nb] = *(const f16x8*)&lsB[cur][(row << 6) + ((cb ^ (row & 7)) << 3)];
      }
      __builtin_amdgcn_s_setprio(1);
      #pragma unroll
      for (int mb = 0; mb < 8; ++mb)
        #pragma unroll
        for (int nb = 0; nb < 4; ++nb)
          acc[mb][nb] = __builtin_amdgcn_mfma_f32_16x16x32_f16(av[mb], bv[nb], acc[mb][nb], 0, 0, 0);
      __builtin_amdgcn_s_setprio(0);
    }
    __syncthreads();
    cur ^= 1;
  }

  const int mb0 = blockIdx.x * 256 + wm * 128;
  const int nb0 = blockIdx.y * 256 + wn * 64;
  const int cn = lane & 15;
  const int rq = (lane >> 4) << 2;
  float* cf = (float*)Cp;
  unsigned short* ch = (unsigned short*)Cp;
  #pragma unroll
  for (int mb = 0; mb < 8; ++mb) {
    #pragma unroll
    for (int nb = 0; nb < 4; ++nb) {
      int n = nb0 + nb * 16 + cn;
      float bn = bias_n ? bias_n[bz * sBn + n] : 0.f;
      #pragma unroll
      for (int r = 0; r < 4; ++r) {
        int m = mb0 + mb * 16 + rq + r;
        float vv = acc[mb][nb][r] + bn;
        size_t off = (size_t)(bz * sC) + (size_t)m * ldc + n;
        if (out_f32) cf[off] = vv;
        else ch[off] = f2h(vv);
      }
    }
  }
}

extern "C" void kernel_launch(void* const* d_in, const int* in_sizes, int n_in,
                              void* d_out, int out_size, void* d_ws, size_t ws_size,
                              hipStream_t stream) {
  const float* x = (const float*)d_in[0];
  const float* y = (const float*)d_in[1];
  const float* f_w = (const float*)d_in[2];
  const float* f_b = (const float*)d_in[3];
  const float* g_w = (const float*)d_in[4];
  const float* g_b = (const float*)d_in[5];  // dropped: row-constant shift, softmax-exact
  const float* h_w = (const float*)d_in[6];
  const float* h_b = (const float*)d_in[7];
  const float* out_w = (const float*)d_in[8];
  const float* out_b = (const float*)d_in[9];
  float* out = (float*)d_out;
  (void)g_b;

  char* ws = (char*)d_ws;
  size_t off = 0;
  auto alloc = [&](size_t bytes) -> char* {
    char* p = ws + off;
    off += (bytes + 255) & ~(size_t)255;
    return p;
  };
  const size_t TN = (size_t)NB * HW * NC;  // elems per [B][HW][C] buf
  const size_t WN = (size_t)512 * 512;
  float* stats = (float*)alloc(8192 * sizeof(float));
  unsigned short* fwT = (unsigned short*)alloc(WN * 2);
  unsigned short* gwT = (unsigned short*)alloc(WN * 2);
  unsigned short* hwT = (unsigned short*)alloc(WN * 2);
  unsigned short* owB = (unsigned short*)alloc(WN * 2);
  unsigned short* W1T = (unsigned short*)alloc(WN * 2);
  unsigned short* W2 = (unsigned short*)alloc(WN * 2);
  unsigned short* W2x2 = (unsigned short*)alloc((size_t)512 * 1024 * 2);
  float* vv = (float*)alloc(512 * 4);
  float* b2 = (float*)alloc(512 * 4);
  float* wj = (float*)alloc((size_t)NB * HW * 4);
  unsigned short* xnT = (unsigned short*)alloc(TN * 2);
  unsigned short* ynT = (unsigned short*)alloc(TN * 2);
  unsigned short* yH = (unsigned short*)alloc(TN * 2);
  unsigned short* fB = (unsigned short*)alloc(TN * 2);    // F2
  unsigned short* Zp = (unsigned short*)alloc((size_t)NB * HW * 1024 * 2);  // 32MB
  size_t remain = ws_size > off ? ws_size - off : 0;
  // per-batch attention footprint: S f16 only (32MB)
  const size_t SB = (size_t)HW * HW * 2;
  int G, R = HW;
  if (remain >= 4 * SB)      { G = 4; }
  else if (remain >= 2 * SB) { G = 2; }
  else if (remain >= SB)     { G = 1; }
  else {
    G = 1;
    while (R > 128 && (size_t)R * HW * 2 > remain) R >>= 1;
  }
  unsigned short* Sh = (unsigned short*)alloc((size_t)G * R * HW * 2);
  if (off > ws_size) return;  // scratch too small; cannot run

  const long long PS = (long long)HW * NC;  // per-batch stride (elements)
  const int BIG = 1 << 30;

  castw_k<<<dim3(8, 8, 4), dim3(256), 0, stream>>>(f_w, g_w, h_w, out_w,
                                                   fwT, gwT, hwT, owB);
  moments_k<<<dim3(4096), dim3(256), 0, stream>>>(x, y, stats);
  transnorm_k<<<dim3(64, 8, 8), dim3(256), 0, stream>>>(x, y, stats, xnT, ynT, yH);

  // v[c] = sum_o Gw[o][c] f_b[o] ; b2[o] = out_b[o] + sum_c OutW[o][c] h_b[c]
  dotrows_h<<<dim3(128), dim3(256), 0, stream>>>(gwT, f_b, vv);
  b2_k<<<dim3(128), dim3(256), 0, stream>>>(out_w, h_b, out_b, b2);
  // W1T[c2][c1] = sum_o Gw[o][c2] Fw[o][c1]   (= (Fw^T Gw)^T, F2's B-operand)
  gemm_ntp<<<dim3(4, 4, 1), dim3(256), 0, stream>>>(
      gwT, 0, 512, fwT, 0, 512, W1T, 0, 0, 512, 512, 0, 0,
      nullptr, nullptr, nullptr, 0, nullptr, nullptr, BIG);
  // W2[o][c'] = sum_c OutW[o][c] Hw[c][c']
  gemm_ntp<<<dim3(4, 4, 1), dim3(256), 0, stream>>>(
      owB, 0, 512, hwT, 0, 512, W2, 0, 0, 512, 512, 0, 0,
      nullptr, nullptr, nullptr, 0, nullptr, nullptr, BIG);
  repl_k<<<dim3(256), dim3(256), 0, stream>>>(W2, W2x2);
  // w[b][j] = Yn[b][j] . v
  dotrows_h<<<dim3(NB * HW / 4), dim3(256), 0, stream>>>(ynT, vv, wj);
  // F2[b][i][c'] = Xn . W1
  gemm_ntp<<<dim3(32, 4, NB), dim3(256), 0, stream>>>(
      xnT, PS, NC, W1T, 0, NC, fB, PS, 0, NC, NC, 0, 0,
      nullptr, nullptr, nullptr, 0, nullptr, nullptr, BIG);

  for (int b0 = 0; b0 < NB; b0 += G) {
    for (int r0 = 0; r0 < HW; r0 += R) {
      if (R >= 256) {
        // E[bg][i][j] = F2[i][:] . Yn[j][:] + w[bg][j]  -> f16, pitch HW
        gemm_nt2<<<dim3(R / 256, HW / 256, G), dim3(512), 0, stream>>>(
            fB + ((size_t)b0 * HW + r0) * NC, PS, NC,
            ynT + (size_t)b0 * PS, PS, NC,
            Sh, (long long)R * HW, HW, NC, 0,
            wj + (size_t)b0 * HW, HW);
      } else {
        gemm_ntp<<<dim3(R / 128, 32, G), dim3(256), 0, stream>>>(
            fB + ((size_t)b0 * HW + r0) * NC, PS, NC,
            ynT + (size_t)b0 * PS, PS, NC,
            Sh, (long long)R * HW, 0, HW, NC, 0, 0,
            nullptr, wj + (size_t)b0 * HW, nullptr, 0, nullptr, nullptr, BIG);
      }
      // row softmax in place (f16)
      softmax_h<<<dim3(G * R), dim3(256), 0, stream>>>(Sh);
      // Zp[i][sp*512+c'] = P[i][sp-half] . y[c'][sp-half]  (f16, K-interleaved)
      gemm_ntp<<<dim3(R / 128, 4, G * 2), dim3(256), 0, stream>>>(
          Sh, (long long)R * HW, HW,
          yH + (size_t)b0 * NC * HW, (long long)NC * HW, HW,
          Zp + ((size_t)b0 * HW + r0) * 1024, (long long)R * 1024, 512, 1024,
          HW / 2, 0, 1,
          nullptr, nullptr, nullptr, 0, nullptr, nullptr, BIG);
    }
  }
  // out[b][o][i] = W2x2 . Zp^T + b2[o] + x   (f32 out; K=1024 folds the 2 splits)
  gemm_ntp<<<dim3(4, 32, NB), dim3(256), 0, stream>>>(
      W2x2, 0, 1024, Zp, (long long)HW * 1024, 1024,
      out, (long long)NC * HW, 0, HW, 1024, 1, 0,
      b2, nullptr, x, (long long)NC * HW, nullptr, nullptr, BIG);
}